// Round 7
// baseline (284.712 us; speedup 1.0000x reference)
//
#include <hip/hip_runtime.h>
#include <hip/hip_bf16.h>

// Round 7: depth-2 register prefetch in both GEMMs (load slab k+2 while computing
// slab k, write slab k+1 -> vmcnt wait lands a FULL iteration after load issue);
// hs fp32->bf16 fused into gemm1 A-staging (cvt3 -> cvt2, weights only);
// pack_qk+pack_v merged into one launch. Attention unchanged from round 6.
//
// ws layout:
//   [A] qkv_b16: 3072*3840 bf16 (23.6 MB)
//   [B] spare  : 3072*1280 bf16 (7.9 MB)  -- attn_b output
//   [C] qkvw_b : 3840*1280 bf16 (9.8 MB)  -- reused as Qp after gemm1
//   [D] projw_b: 1280*1280 bf16 (3.3 MB)
//   [E] Kp     : 3*16*16*6144 bf16 (9.4 MB)
//   [F] Vp     : 3*16*16*6144 bf16 (9.4 MB)  (96-wide, col80 = ones)

#define S_TOT 3072
#define DIM   1280
#define NH    16
#define HD    80
#define SEG   1024
#define TDIM  3840

typedef short v8s __attribute__((ext_vector_type(8)));
typedef float v4f __attribute__((ext_vector_type(4)));

__device__ __forceinline__ void load_lds16(const void* g, void* l) {
  __builtin_amdgcn_global_load_lds(
      (const __attribute__((address_space(1))) unsigned int*)g,
      (__attribute__((address_space(3))) unsigned int*)l, 16, 0, 0);
}

__device__ __forceinline__ short f2bf(float v) {
  __hip_bfloat16 b = __float2bfloat16(v);
  return *reinterpret_cast<short*>(&b);
}

__device__ __forceinline__ float bf2f(short s) {
  unsigned u = ((unsigned)(unsigned short)s) << 16;
  float f;
  __builtin_memcpy(&f, &u, 4);
  return f;
}

// weights fp32->bf16 (hs conversion is fused into gemm1)
#define CVT_N2 (TDIM * DIM / 4)
#define CVT_N3 (DIM * DIM / 4)
__global__ __launch_bounds__(256) void cvt2(const float* __restrict__ in2,
                                            const float* __restrict__ in3,
                                            __hip_bfloat16* __restrict__ o2,
                                            __hip_bfloat16* __restrict__ o3) {
  int i = blockIdx.x * 256 + threadIdx.x;
  const float* in;
  __hip_bfloat16* out;
  if (i < CVT_N2) { in = in2; out = o2; }
  else { in = in3; out = o3; i -= CVT_N2; }
  const float4 v = ((const float4*)in)[i];
  __hip_bfloat162 p0, p1;
  p0.x = __float2bfloat16(v.x); p0.y = __float2bfloat16(v.y);
  p1.x = __float2bfloat16(v.z); p1.y = __float2bfloat16(v.w);
  __hip_bfloat162* o = (__hip_bfloat162*)(out + (size_t)i * 4);
  o[0] = p0; o[1] = p1;
}

// ---------------- gemm1: 128x128, BK=32, depth-2 prefetch, A = fp32 ----------------
// C[M,N] = A[M,K] @ B[N,K]^T + bias[N], C bf16; grid (N/128, M/128); K%32==0, nk>=3.
__global__ __launch_bounds__(256) void gemm1_f32a(const float* __restrict__ A,
                                                  const __hip_bfloat16* __restrict__ B,
                                                  const float* __restrict__ bias,
                                                  __hip_bfloat16* __restrict__ C,
                                                  int M, int N, int K) {
  __shared__ __align__(16) short Abuf[2][4096];  // 16 KB
  __shared__ __align__(16) short Bbuf[2][4096];  // 16 KB
  const int tid  = threadIdx.x;
  const int wave = tid >> 6;
  const int lane = tid & 63;
  const int bm = blockIdx.y * 128;
  const int bn = blockIdx.x * 128;
  const int wm = (wave >> 1) * 64;
  const int wn = (wave & 1) * 64;

  const int r0 = tid & 127, kh0 = tid >> 7;
  const float* Ag = A + (size_t)(bm + r0) * K + kh0 * 8;           // a0 @+0, a1 @+16 floats
  const __hip_bfloat16* Bg0 = B + (size_t)(bn + r0) * K + kh0 * 8;
  const __hip_bfloat16* Bg1 = Bg0 + 16;

  v4f acc[4][4];
  const v4f vz = {0.f, 0.f, 0.f, 0.f};
  #pragma unroll
  for (int i = 0; i < 4; ++i)
    #pragma unroll
    for (int j = 0; j < 4; ++j) acc[i][j] = vz;

  const int kh = lane >> 4;
  const int lr = lane & 15;
  const int nk = K >> 5;

  float4 fa[2][4];      // per-set raw A floats (slab: a0 = fa[s][0..1], a1 = fa[s][2..3])
  v8s nb0[2], nb1[2];   // per-set B

  // prologue: load slab0 -> set0, slab1 -> set1; write slab0 -> buf0
  #pragma unroll
  for (int s = 0; s < 2; ++s) {
    const int off = s * 32;
    fa[s][0] = *(const float4*)(Ag + off);
    fa[s][1] = *(const float4*)(Ag + off + 4);
    fa[s][2] = *(const float4*)(Ag + off + 16);
    fa[s][3] = *(const float4*)(Ag + off + 20);
    nb0[s] = *(const v8s*)(Bg0 + off);
    nb1[s] = *(const v8s*)(Bg1 + off);
  }
  {
    v8s a0, a1;
    #pragma unroll
    for (int e = 0; e < 4; ++e) {
      a0[e]     = f2bf(fa[0][0][e]); a0[e + 4] = f2bf(fa[0][1][e]);
      a1[e]     = f2bf(fa[0][2][e]); a1[e + 4] = f2bf(fa[0][3][e]);
    }
    *(v8s*)&Abuf[0][tid * 8] = a0;  *(v8s*)&Abuf[0][(tid + 256) * 8] = a1;
    *(v8s*)&Bbuf[0][tid * 8] = nb0[0];  *(v8s*)&Bbuf[0][(tid + 256) * 8] = nb1[0];
  }
  __syncthreads();

  #define G1_LOAD(SET, SLAB)                                        \
    { const int off = (SLAB) * 32;                                  \
      fa[SET][0] = *(const float4*)(Ag + off);                      \
      fa[SET][1] = *(const float4*)(Ag + off + 4);                  \
      fa[SET][2] = *(const float4*)(Ag + off + 16);                 \
      fa[SET][3] = *(const float4*)(Ag + off + 20);                 \
      nb0[SET] = *(const v8s*)(Bg0 + off);                          \
      nb1[SET] = *(const v8s*)(Bg1 + off); }

  #define G1_COMPUTE(BUF)                                                          \
    { v8s af[4], bf[4];                                                            \
      _Pragma("unroll")                                                            \
      for (int i = 0; i < 4; ++i) {                                                \
        af[i] = *(const v8s*)&Abuf[BUF][(kh * 128 + wm + i * 16 + lr) * 8];        \
        bf[i] = *(const v8s*)&Bbuf[BUF][(kh * 128 + wn + i * 16 + lr) * 8];        \
      }                                                                            \
      _Pragma("unroll")                                                            \
      for (int i = 0; i < 4; ++i)                                                  \
        _Pragma("unroll")                                                          \
        for (int j = 0; j < 4; ++j)                                                \
          acc[i][j] = __builtin_amdgcn_mfma_f32_16x16x32_bf16(af[i], bf[j],        \
                                                              acc[i][j], 0, 0, 0); }

  #define G1_WRITE(SET, BUF)                                        \
    { v8s a0, a1;                                                   \
      _Pragma("unroll")                                             \
      for (int e = 0; e < 4; ++e) {                                 \
        a0[e] = f2bf(fa[SET][0][e]); a0[e + 4] = f2bf(fa[SET][1][e]); \
        a1[e] = f2bf(fa[SET][2][e]); a1[e + 4] = f2bf(fa[SET][3][e]); \
      }                                                             \
      *(v8s*)&Abuf[BUF][tid * 8] = a0;                              \
      *(v8s*)&Abuf[BUF][(tid + 256) * 8] = a1;                      \
      *(v8s*)&Bbuf[BUF][tid * 8] = nb0[SET];                        \
      *(v8s*)&Bbuf[BUF][(tid + 256) * 8] = nb1[SET]; }

  for (int k = 0; k < nk; k += 2) {
    // even iter k: load slab k+2 -> set0, compute buf0, write slab k+1 (set1) -> buf1
    if (k + 2 < nk) G1_LOAD(0, k + 2);
    G1_COMPUTE(0);
    G1_WRITE(1, 1);
    __syncthreads();
    // odd iter k+1: load slab k+3 -> set1, compute buf1, write slab k+2 (set0) -> buf0
    if (k + 3 < nk) G1_LOAD(1, k + 3);
    G1_COMPUTE(1);
    if (k + 2 < nk) { G1_WRITE(0, 0); }
    __syncthreads();
  }

  const int lq = lane >> 4;
  #pragma unroll
  for (int j = 0; j < 4; ++j) {
    const int col = bn + wn + j * 16 + lr;
    const float bj = bias[col];
    #pragma unroll
    for (int i = 0; i < 4; ++i) {
      const int row0 = bm + wm + i * 16 + lq * 4;
      #pragma unroll
      for (int r = 0; r < 4; ++r)
        C[(size_t)(row0 + r) * N + col] = __float2bfloat16(acc[i][j][r] + bj);
    }
  }
}

// ---------------- gemm2: 64x128, BK=32, depth-2 prefetch, A/B bf16, C fp32 -------
__global__ __launch_bounds__(256) void gemm2_db(const __hip_bfloat16* __restrict__ A,
                                                const __hip_bfloat16* __restrict__ B,
                                                const float* __restrict__ bias,
                                                float* __restrict__ C,
                                                int M, int N, int K) {
  __shared__ __align__(16) short Abuf[2][2048];  // 8 KB
  __shared__ __align__(16) short Bbuf[2][4096];  // 16 KB
  const int tid  = threadIdx.x;
  const int wave = tid >> 6;
  const int lane = tid & 63;
  const int quad = lane >> 4;
  const int l16  = lane & 15;
  const int bm = blockIdx.y * 64;
  const int bn = blockIdx.x * 128;
  const int wm = (wave & 1) * 32;
  const int wn = (wave >> 1) * 64;

  const __hip_bfloat16* Ag  = A + (size_t)(bm + (tid & 63)) * K + (tid >> 6) * 8;
  const __hip_bfloat16* Bg0 = B + (size_t)(bn + (tid & 127)) * K + (tid >> 7) * 8;
  const __hip_bfloat16* Bg1 = Bg0 + 16;

  v4f acc[2][4];
  const v4f vz = {0.f, 0.f, 0.f, 0.f};
  #pragma unroll
  for (int i = 0; i < 2; ++i)
    #pragma unroll
    for (int j = 0; j < 4; ++j) acc[i][j] = vz;

  const int nk = K >> 5;
  v8s na[2], nb0[2], nb1[2];

  #pragma unroll
  for (int s = 0; s < 2; ++s) {
    const int off = s * 32;
    na[s]  = *(const v8s*)(Ag + off);
    nb0[s] = *(const v8s*)(Bg0 + off);
    nb1[s] = *(const v8s*)(Bg1 + off);
  }
  *(v8s*)&Abuf[0][tid * 8] = na[0];
  *(v8s*)&Bbuf[0][tid * 8] = nb0[0];  *(v8s*)&Bbuf[0][(tid + 256) * 8] = nb1[0];
  __syncthreads();

  #define G2_LOAD(SET, SLAB)                       \
    { const int off = (SLAB) * 32;                 \
      na[SET]  = *(const v8s*)(Ag + off);          \
      nb0[SET] = *(const v8s*)(Bg0 + off);         \
      nb1[SET] = *(const v8s*)(Bg1 + off); }

  #define G2_COMPUTE(BUF)                                                          \
    { v8s af[2], bf[4];                                                            \
      _Pragma("unroll")                                                            \
      for (int i = 0; i < 2; ++i)                                                  \
        af[i] = *(const v8s*)&Abuf[BUF][(quad * 64 + wm + i * 16 + l16) * 8];      \
      _Pragma("unroll")                                                            \
      for (int j = 0; j < 4; ++j)                                                  \
        bf[j] = *(const v8s*)&Bbuf[BUF][(quad * 128 + wn + j * 16 + l16) * 8];     \
      _Pragma("unroll")                                                            \
      for (int i = 0; i < 2; ++i)                                                  \
        _Pragma("unroll")                                                          \
        for (int j = 0; j < 4; ++j)                                                \
          acc[i][j] = __builtin_amdgcn_mfma_f32_16x16x32_bf16(af[i], bf[j],        \
                                                              acc[i][j], 0, 0, 0); }

  #define G2_WRITE(SET, BUF)                                        \
    { *(v8s*)&Abuf[BUF][tid * 8] = na[SET];                         \
      *(v8s*)&Bbuf[BUF][tid * 8] = nb0[SET];                        \
      *(v8s*)&Bbuf[BUF][(tid + 256) * 8] = nb1[SET]; }

  for (int k = 0; k < nk; k += 2) {
    if (k + 2 < nk) G2_LOAD(0, k + 2);
    G2_COMPUTE(0);
    G2_WRITE(1, 1);
    __syncthreads();
    if (k + 3 < nk) G2_LOAD(1, k + 3);
    G2_COMPUTE(1);
    if (k + 2 < nk) { G2_WRITE(0, 0); }
    __syncthreads();
  }

  #pragma unroll
  for (int j = 0; j < 4; ++j) {
    const int col = bn + wn + j * 16 + l16;
    const float bj = bias[col];
    #pragma unroll
    for (int i = 0; i < 2; ++i) {
      const int row0 = bm + wm + i * 16 + quad * 4;
      #pragma unroll
      for (int r = 0; r < 4; ++r)
        C[(size_t)(row0 + r) * N + col] = acc[i][j][r] + bj;
    }
  }
}

// ---------------- merged pack kernel ----------------
// blocks [0, QK_BLOCKS): pack_qk; rest: pack_v
#define QK_BLOCKS ((2 * S_TOT * 16 * 12) / 256)   // 4608
#define V_BLOCKS  ((3 * 16 * 16 * 8 * 96) / 256)  // 2304
__global__ __launch_bounds__(256) void pack_all(const __hip_bfloat16* __restrict__ qkv,
                                                const float* __restrict__ cos_,
                                                const float* __restrict__ sin_,
                                                short* __restrict__ Qp,
                                                short* __restrict__ Kp,
                                                short* __restrict__ Vp) {
  const int bid = blockIdx.x;
  if (bid < QK_BLOCKS) {
    const int idx = bid * 256 + threadIdx.x;
    const int kd = idx % 12;
    const int h  = (idx / 12) % 16;
    const int s  = (idx / 192) % S_TOT;
    const int p  = idx / (192 * S_TOT);
    const int seg = s >> 10, tb = (s >> 6) & 15, t = s & 63;
    short* out = (p ? Kp : Qp) +
                 ((size_t)(((seg * 16 + h) * 16 + tb) * 12 + kd) * 64 + t) * 8;
    short tmp[8];
    if (kd >= 10) {
      #pragma unroll
      for (int j = 0; j < 8; ++j) tmp[j] = 0;
      *(int4*)out = *(int4*)tmp;
      return;
    }
    const short* row = (const short*)qkv + (size_t)s * TDIM + p * DIM + h * HD;
    const int d0 = kd * 8;
    const v8s xm = *(const v8s*)(row + d0);
    const v8s xr = *(const v8s*)(row + d0 + ((kd < 5) ? 40 : -40));
    const float sgn = (kd < 5) ? -1.f : 1.f;
    const float scale = (p == 0) ? 0.111803398874989485f : 1.0f;
    #pragma unroll
    for (int j = 0; j < 8; ++j) {
      const int d = d0 + j;
      const float v = (bf2f(xm[j]) * cos_[s * HD + d] +
                       sgn * bf2f(xr[j]) * sin_[s * HD + d]) * scale;
      tmp[j] = f2bf(v);
    }
    *(int4*)out = *(int4*)tmp;
  } else {
    const int idx = (bid - QK_BLOCKS) * 256 + threadIdx.x;
    const int d  = idx % 96;
    const int td = (idx / 96) % 8;
    const int tb = (idx / 768) % 16;
    const int h  = (idx / (768 * 16)) % 16;
    const int seg = idx / (768 * 256);
    const int s0 = seg * SEG + tb * 64 + td * 8;
    const short* q = (const short*)qkv;
    short tmp[8];
    if (d < 80) {
      #pragma unroll
      for (int j = 0; j < 8; ++j)
        tmp[j] = q[(size_t)(s0 + j) * TDIM + 2 * DIM + h * HD + d];
    } else {
      const short fill = (d == 80) ? (short)0x3F80 : (short)0;
      #pragma unroll
      for (int j = 0; j < 8; ++j) tmp[j] = fill;
    }
    *(int4*)(Vp + (size_t)idx * 8) = *(int4*)tmp;
  }
}

// ---------------- flash MFMA attention, no-max softmax (unchanged) ----------------
__global__ __launch_bounds__(256, 3) void attn_mfma(const short* __restrict__ Qp,
                                                    const short* __restrict__ Kp,
                                                    const short* __restrict__ Vp,
                                                    __hip_bfloat16* __restrict__ out) {
  __shared__ __align__(16) short Qs[64 * 96];
  __shared__ __align__(16) short Ks[64 * 96];
  __shared__ __align__(16) short Vs[8 * 96 * 8];
  __shared__ __align__(16) short Ps[4][16 * 68];

  const int qt  = blockIdx.x;
  const int h   = blockIdx.y;
  const int seg = blockIdx.z;
  const int tid  = threadIdx.x;
  const int wave = tid >> 6;
  const int lane = tid & 63;
  const int quad = lane >> 4;
  const int l16  = lane & 15;
  const int sh16 = seg * 16 + h;

  const short* Qg = Qp + (size_t)(sh16 * 16 + qt) * 6144;
  #pragma unroll
  for (int it = 0; it < 3; ++it)
    load_lds16(Qg + (it * 256 + tid) * 8, &Qs[(it * 256 + wave * 64) * 8]);
  __syncthreads();

  v8s af[3];
  #pragma unroll
  for (int ks = 0; ks < 3; ++ks)
    af[ks] = *(const v8s*)&Qs[((ks * 4 + quad) * 64 + wave * 16 + l16) * 8];

  v4f o4[6];
  const v4f vz = {0.f, 0.f, 0.f, 0.f};
  #pragma unroll
  for (int n = 0; n < 6; ++n) o4[n] = vz;

  for (int kb = 0; kb < 16; ++kb) {
    __syncthreads();
    const short* Kg = Kp + (size_t)(sh16 * 16 + kb) * 6144;
    const short* Vg = Vp + (size_t)(sh16 * 16 + kb) * 6144;
    #pragma unroll
    for (int it = 0; it < 3; ++it) {
      load_lds16(Kg + (it * 256 + tid) * 8, &Ks[(it * 256 + wave * 64) * 8]);
      load_lds16(Vg + (it * 256 + tid) * 8, &Vs[(it * 256 + wave * 64) * 8]);
    }
    __syncthreads();

    v4f s4[4];
    #pragma unroll
    for (int j = 0; j < 4; ++j) {
      s4[j] = vz;
      #pragma unroll
      for (int ks = 0; ks < 3; ++ks) {
        const v8s bf = *(const v8s*)&Ks[((ks * 4 + quad) * 64 + j * 16 + l16) * 8];
        s4[j] = __builtin_amdgcn_mfma_f32_16x16x32_bf16(af[ks], bf, s4[j], 0, 0, 0);
      }
    }

    #pragma unroll
    for (int reg = 0; reg < 4; ++reg)
      #pragma unroll
      for (int j = 0; j < 4; ++j)
        Ps[wave][(quad * 4 + reg) * 68 + j * 16 + l16] = f2bf(__expf(s4[j][reg]));

    v8s pa[2];
    #pragma unroll
    for (int kp = 0; kp < 2; ++kp)
      pa[kp] = *(const v8s*)&Ps[wave][l16 * 68 + kp * 32 + quad * 8];
    #pragma unroll
    for (int n = 0; n < 6; ++n) {
      #pragma unroll
      for (int kp = 0; kp < 2; ++kp) {
        const v8s vb = *(const v8s*)&Vs[((kp * 4 + quad) * 96 + n * 16 + l16) * 8];
        o4[n] = __builtin_amdgcn_mfma_f32_16x16x32_bf16(pa[kp], vb, o4[n], 0, 0, 0);
      }
    }
  }

  float inv[4];
  #pragma unroll
  for (int r = 0; r < 4; ++r)
    inv[r] = 1.f / __shfl(o4[5][r], quad << 4);
  const int row0 = seg * SEG + qt * 64 + wave * 16 + quad * 4;
  #pragma unroll
  for (int n = 0; n < 5; ++n) {
    const int col = h * HD + n * 16 + l16;
    #pragma unroll
    for (int r = 0; r < 4; ++r)
      out[(size_t)(row0 + r) * DIM + col] = __float2bfloat16(o4[n][r] * inv[r]);
  }
}

extern "C" void kernel_launch(void* const* d_in, const int* in_sizes, int n_in,
                              void* d_out, int out_size, void* d_ws, size_t ws_size,
                              hipStream_t stream) {
  (void)in_sizes; (void)n_in; (void)out_size; (void)ws_size;
  const float* hs     = (const float*)d_in[0];
  const float* cosp   = (const float*)d_in[1];
  const float* sinp   = (const float*)d_in[2];
  const float* qkv_w  = (const float*)d_in[3];
  const float* qkv_b  = (const float*)d_in[4];
  const float* proj_w = (const float*)d_in[5];
  const float* proj_b = (const float*)d_in[6];

  float* out_f = (float*)d_out;
  __hip_bfloat16* qkv_b16 = (__hip_bfloat16*)d_ws;                     // [A]
  __hip_bfloat16* attn_b  = qkv_b16 + (size_t)S_TOT * TDIM;            // [B]
  __hip_bfloat16* qkvw_b  = attn_b + (size_t)S_TOT * DIM;              // [C]
  __hip_bfloat16* projw_b = qkvw_b + (size_t)TDIM * DIM;               // [D]
  short* Qp = (short*)qkvw_b;                                          // alias [C]
  short* Kp = (short*)(projw_b + (size_t)DIM * DIM);                   // [E]
  short* Vp = Kp + (size_t)3 * 16 * 16 * 6144;                         // [F]

  cvt2<<<(CVT_N2 + CVT_N3) / 256, 256, 0, stream>>>(qkv_w, proj_w, qkvw_b, projw_b);

  gemm1_f32a<<<dim3(TDIM / 128, S_TOT / 128), 256, 0, stream>>>(
      hs, qkvw_b, qkv_b, qkv_b16, S_TOT, TDIM, DIM);

  pack_all<<<QK_BLOCKS + V_BLOCKS, 256, 0, stream>>>(qkv_b16, cosp, sinp, Qp, Kp, Vp);

  attn_mfma<<<dim3(16, NH, 3), 256, 0, stream>>>(Qp, Kp, Vp, attn_b);

  gemm2_db<<<dim3(DIM / 128, S_TOT / 64), 256, 0, stream>>>(
      attn_b, projw_b, proj_b, out_f, S_TOT, DIM, DIM);
}

// Round 8
// 262.805 us; speedup vs baseline: 1.0834x; 1.0834x over previous
//
#include <hip/hip_runtime.h>
#include <hip/hip_bf16.h>

// Round 8:
//  gemm1: bf16 A RESTORED (r7's fused fp32-A read doubled L2-miss traffic: FETCH
//         65.8->117.5 MB = the whole regression). Depth-2 register prefetch kept.
//  attn:  staging restructured like r6's GEMM win — plain global loads -> regs
//         (issued before compute), compute, barrier, ds_write, barrier. The vmcnt
//         wait sits a full compute phase after issue. Single K/V buffer, 3 blk/CU.
//  cvt3 (hs+weights), pack_all, gemm2 as before.
//
// ws layout:
//   [A] qkv_b16: 3072*3840 bf16 (23.6 MB)
//   [B] hs_b   : 3072*1280 bf16 (7.9 MB)  -- reused as attn_b after gemm1
//   [C] qkvw_b : 3840*1280 bf16 (9.8 MB)  -- reused as Qp after gemm1
//   [D] projw_b: 1280*1280 bf16 (3.3 MB)
//   [E] Kp     : 3*16*16*6144 bf16 (9.4 MB)
//   [F] Vp     : 3*16*16*6144 bf16 (9.4 MB)  (96-wide, col80 = ones)

#define S_TOT 3072
#define DIM   1280
#define NH    16
#define HD    80
#define SEG   1024
#define TDIM  3840

typedef short v8s __attribute__((ext_vector_type(8)));
typedef float v4f __attribute__((ext_vector_type(4)));

__device__ __forceinline__ short f2bf(float v) {
  __hip_bfloat16 b = __float2bfloat16(v);
  return *reinterpret_cast<short*>(&b);
}

__device__ __forceinline__ float bf2f(short s) {
  unsigned u = ((unsigned)(unsigned short)s) << 16;
  float f;
  __builtin_memcpy(&f, &u, 4);
  return f;
}

// fused fp32->bf16 for hs / qkv_w / proj_w (one launch)
#define CVT_N1 (S_TOT * DIM / 4)
#define CVT_N2 (TDIM * DIM / 4)
#define CVT_N3 (DIM * DIM / 4)
__global__ __launch_bounds__(256) void cvt3(const float* __restrict__ in1,
                                            const float* __restrict__ in2,
                                            const float* __restrict__ in3,
                                            __hip_bfloat16* __restrict__ o1,
                                            __hip_bfloat16* __restrict__ o2,
                                            __hip_bfloat16* __restrict__ o3) {
  int i = blockIdx.x * 256 + threadIdx.x;
  const float* in;
  __hip_bfloat16* out;
  if (i < CVT_N1) { in = in1; out = o1; }
  else if (i < CVT_N1 + CVT_N2) { in = in2; out = o2; i -= CVT_N1; }
  else { in = in3; out = o3; i -= CVT_N1 + CVT_N2; }
  const float4 v = ((const float4*)in)[i];
  __hip_bfloat162 p0, p1;
  p0.x = __float2bfloat16(v.x); p0.y = __float2bfloat16(v.y);
  p1.x = __float2bfloat16(v.z); p1.y = __float2bfloat16(v.w);
  __hip_bfloat162* o = (__hip_bfloat162*)(out + (size_t)i * 4);
  o[0] = p0; o[1] = p1;
}

// ---------------- gemm1: 128x128, BK=32, depth-2 reg prefetch, bf16 A/B -------
__global__ __launch_bounds__(256) void gemm128_db2(const __hip_bfloat16* __restrict__ A,
                                                   const __hip_bfloat16* __restrict__ B,
                                                   const float* __restrict__ bias,
                                                   __hip_bfloat16* __restrict__ C,
                                                   int M, int N, int K) {
  __shared__ __align__(16) short Abuf[2][4096];  // 16 KB
  __shared__ __align__(16) short Bbuf[2][4096];  // 16 KB
  const int tid  = threadIdx.x;
  const int wave = tid >> 6;
  const int lane = tid & 63;
  const int bm = blockIdx.y * 128;
  const int bn = blockIdx.x * 128;
  const int wm = (wave >> 1) * 64;
  const int wn = (wave & 1) * 64;

  const int r0 = tid & 127, kh0 = tid >> 7;
  const __hip_bfloat16* Ag0 = A + (size_t)(bm + r0) * K + kh0 * 8;
  const __hip_bfloat16* Ag1 = Ag0 + 16;  // kh0+2
  const __hip_bfloat16* Bg0 = B + (size_t)(bn + r0) * K + kh0 * 8;
  const __hip_bfloat16* Bg1 = Bg0 + 16;

  v4f acc[4][4];
  const v4f vz = {0.f, 0.f, 0.f, 0.f};
  #pragma unroll
  for (int i = 0; i < 4; ++i)
    #pragma unroll
    for (int j = 0; j < 4; ++j) acc[i][j] = vz;

  const int kh = lane >> 4;
  const int lr = lane & 15;
  const int nk = K >> 5;  // 40

  v8s ra0[2], ra1[2], rb0[2], rb1[2];
  #pragma unroll
  for (int s = 0; s < 2; ++s) {
    const int off = s * 32;
    ra0[s] = *(const v8s*)(Ag0 + off);
    ra1[s] = *(const v8s*)(Ag1 + off);
    rb0[s] = *(const v8s*)(Bg0 + off);
    rb1[s] = *(const v8s*)(Bg1 + off);
  }
  *(v8s*)&Abuf[0][tid * 8] = ra0[0];  *(v8s*)&Abuf[0][(tid + 256) * 8] = ra1[0];
  *(v8s*)&Bbuf[0][tid * 8] = rb0[0];  *(v8s*)&Bbuf[0][(tid + 256) * 8] = rb1[0];
  __syncthreads();

  #define G1_LOAD(SET, SLAB)                          \
    { const int off = (SLAB) * 32;                    \
      ra0[SET] = *(const v8s*)(Ag0 + off);            \
      ra1[SET] = *(const v8s*)(Ag1 + off);            \
      rb0[SET] = *(const v8s*)(Bg0 + off);            \
      rb1[SET] = *(const v8s*)(Bg1 + off); }

  #define G1_COMPUTE(BUF)                                                          \
    { v8s af[4], bf[4];                                                            \
      _Pragma("unroll")                                                            \
      for (int i = 0; i < 4; ++i) {                                                \
        af[i] = *(const v8s*)&Abuf[BUF][(kh * 128 + wm + i * 16 + lr) * 8];        \
        bf[i] = *(const v8s*)&Bbuf[BUF][(kh * 128 + wn + i * 16 + lr) * 8];        \
      }                                                                            \
      _Pragma("unroll")                                                            \
      for (int i = 0; i < 4; ++i)                                                  \
        _Pragma("unroll")                                                          \
        for (int j = 0; j < 4; ++j)                                                \
          acc[i][j] = __builtin_amdgcn_mfma_f32_16x16x32_bf16(af[i], bf[j],        \
                                                              acc[i][j], 0, 0, 0); }

  #define G1_WRITE(SET, BUF)                                        \
    { *(v8s*)&Abuf[BUF][tid * 8] = ra0[SET];                        \
      *(v8s*)&Abuf[BUF][(tid + 256) * 8] = ra1[SET];                \
      *(v8s*)&Bbuf[BUF][tid * 8] = rb0[SET];                        \
      *(v8s*)&Bbuf[BUF][(tid + 256) * 8] = rb1[SET]; }

  for (int k = 0; k < nk; k += 2) {
    if (k + 2 < nk) G1_LOAD(0, k + 2);
    G1_COMPUTE(0);
    G1_WRITE(1, 1);
    __syncthreads();
    if (k + 3 < nk) G1_LOAD(1, k + 3);
    G1_COMPUTE(1);
    if (k + 2 < nk) { G1_WRITE(0, 0); }
    __syncthreads();
  }

  const int lq = lane >> 4;
  #pragma unroll
  for (int j = 0; j < 4; ++j) {
    const int col = bn + wn + j * 16 + lr;
    const float bj = bias[col];
    #pragma unroll
    for (int i = 0; i < 4; ++i) {
      const int row0 = bm + wm + i * 16 + lq * 4;
      #pragma unroll
      for (int r = 0; r < 4; ++r)
        C[(size_t)(row0 + r) * N + col] = __float2bfloat16(acc[i][j][r] + bj);
    }
  }
}

// ---------------- gemm2: 64x128, BK=32, depth-2 prefetch, bf16 in, fp32 out ----
__global__ __launch_bounds__(256) void gemm2_db(const __hip_bfloat16* __restrict__ A,
                                                const __hip_bfloat16* __restrict__ B,
                                                const float* __restrict__ bias,
                                                float* __restrict__ C,
                                                int M, int N, int K) {
  __shared__ __align__(16) short Abuf[2][2048];  // 8 KB
  __shared__ __align__(16) short Bbuf[2][4096];  // 16 KB
  const int tid  = threadIdx.x;
  const int wave = tid >> 6;
  const int lane = tid & 63;
  const int quad = lane >> 4;
  const int l16  = lane & 15;
  const int bm = blockIdx.y * 64;
  const int bn = blockIdx.x * 128;
  const int wm = (wave & 1) * 32;
  const int wn = (wave >> 1) * 64;

  const __hip_bfloat16* Ag  = A + (size_t)(bm + (tid & 63)) * K + (tid >> 6) * 8;
  const __hip_bfloat16* Bg0 = B + (size_t)(bn + (tid & 127)) * K + (tid >> 7) * 8;
  const __hip_bfloat16* Bg1 = Bg0 + 16;

  v4f acc[2][4];
  const v4f vz = {0.f, 0.f, 0.f, 0.f};
  #pragma unroll
  for (int i = 0; i < 2; ++i)
    #pragma unroll
    for (int j = 0; j < 4; ++j) acc[i][j] = vz;

  const int nk = K >> 5;
  v8s na[2], nb0[2], nb1[2];

  #pragma unroll
  for (int s = 0; s < 2; ++s) {
    const int off = s * 32;
    na[s]  = *(const v8s*)(Ag + off);
    nb0[s] = *(const v8s*)(Bg0 + off);
    nb1[s] = *(const v8s*)(Bg1 + off);
  }
  *(v8s*)&Abuf[0][tid * 8] = na[0];
  *(v8s*)&Bbuf[0][tid * 8] = nb0[0];  *(v8s*)&Bbuf[0][(tid + 256) * 8] = nb1[0];
  __syncthreads();

  #define G2_LOAD(SET, SLAB)                       \
    { const int off = (SLAB) * 32;                 \
      na[SET]  = *(const v8s*)(Ag + off);          \
      nb0[SET] = *(const v8s*)(Bg0 + off);         \
      nb1[SET] = *(const v8s*)(Bg1 + off); }

  #define G2_COMPUTE(BUF)                                                          \
    { v8s af[2], bf[4];                                                            \
      _Pragma("unroll")                                                            \
      for (int i = 0; i < 2; ++i)                                                  \
        af[i] = *(const v8s*)&Abuf[BUF][(quad * 64 + wm + i * 16 + l16) * 8];      \
      _Pragma("unroll")                                                            \
      for (int j = 0; j < 4; ++j)                                                  \
        bf[j] = *(const v8s*)&Bbuf[BUF][(quad * 128 + wn + j * 16 + l16) * 8];     \
      _Pragma("unroll")                                                            \
      for (int i = 0; i < 2; ++i)                                                  \
        _Pragma("unroll")                                                          \
        for (int j = 0; j < 4; ++j)                                                \
          acc[i][j] = __builtin_amdgcn_mfma_f32_16x16x32_bf16(af[i], bf[j],        \
                                                              acc[i][j], 0, 0, 0); }

  #define G2_WRITE(SET, BUF)                                        \
    { *(v8s*)&Abuf[BUF][tid * 8] = na[SET];                         \
      *(v8s*)&Bbuf[BUF][tid * 8] = nb0[SET];                        \
      *(v8s*)&Bbuf[BUF][(tid + 256) * 8] = nb1[SET]; }

  for (int k = 0; k < nk; k += 2) {
    if (k + 2 < nk) G2_LOAD(0, k + 2);
    G2_COMPUTE(0);
    G2_WRITE(1, 1);
    __syncthreads();
    if (k + 3 < nk) G2_LOAD(1, k + 3);
    G2_COMPUTE(1);
    if (k + 2 < nk) { G2_WRITE(0, 0); }
    __syncthreads();
  }

  #pragma unroll
  for (int j = 0; j < 4; ++j) {
    const int col = bn + wn + j * 16 + l16;
    const float bj = bias[col];
    #pragma unroll
    for (int i = 0; i < 2; ++i) {
      const int row0 = bm + wm + i * 16 + quad * 4;
      #pragma unroll
      for (int r = 0; r < 4; ++r)
        C[(size_t)(row0 + r) * N + col] = acc[i][j][r] + bj;
    }
  }
}

// ---------------- merged pack kernel ----------------
#define QK_BLOCKS ((2 * S_TOT * 16 * 12) / 256)   // 4608
#define V_BLOCKS  ((3 * 16 * 16 * 8 * 96) / 256)  // 2304
__global__ __launch_bounds__(256) void pack_all(const __hip_bfloat16* __restrict__ qkv,
                                                const float* __restrict__ cos_,
                                                const float* __restrict__ sin_,
                                                short* __restrict__ Qp,
                                                short* __restrict__ Kp,
                                                short* __restrict__ Vp) {
  const int bid = blockIdx.x;
  if (bid < QK_BLOCKS) {
    const int idx = bid * 256 + threadIdx.x;
    const int kd = idx % 12;
    const int h  = (idx / 12) % 16;
    const int s  = (idx / 192) % S_TOT;
    const int p  = idx / (192 * S_TOT);
    const int seg = s >> 10, tb = (s >> 6) & 15, t = s & 63;
    short* out = (p ? Kp : Qp) +
                 ((size_t)(((seg * 16 + h) * 16 + tb) * 12 + kd) * 64 + t) * 8;
    short tmp[8];
    if (kd >= 10) {
      #pragma unroll
      for (int j = 0; j < 8; ++j) tmp[j] = 0;
      *(int4*)out = *(int4*)tmp;
      return;
    }
    const short* row = (const short*)qkv + (size_t)s * TDIM + p * DIM + h * HD;
    const int d0 = kd * 8;
    const v8s xm = *(const v8s*)(row + d0);
    const v8s xr = *(const v8s*)(row + d0 + ((kd < 5) ? 40 : -40));
    const float sgn = (kd < 5) ? -1.f : 1.f;
    const float scale = (p == 0) ? 0.111803398874989485f : 1.0f;
    #pragma unroll
    for (int j = 0; j < 8; ++j) {
      const int d = d0 + j;
      const float v = (bf2f(xm[j]) * cos_[s * HD + d] +
                       sgn * bf2f(xr[j]) * sin_[s * HD + d]) * scale;
      tmp[j] = f2bf(v);
    }
    *(int4*)out = *(int4*)tmp;
  } else {
    const int idx = (bid - QK_BLOCKS) * 256 + threadIdx.x;
    const int d  = idx % 96;
    const int td = (idx / 96) % 8;
    const int tb = (idx / 768) % 16;
    const int h  = (idx / (768 * 16)) % 16;
    const int seg = idx / (768 * 256);
    const int s0 = seg * SEG + tb * 64 + td * 8;
    const short* q = (const short*)qkv;
    short tmp[8];
    if (d < 80) {
      #pragma unroll
      for (int j = 0; j < 8; ++j)
        tmp[j] = q[(size_t)(s0 + j) * TDIM + 2 * DIM + h * HD + d];
    } else {
      const short fill = (d == 80) ? (short)0x3F80 : (short)0;
      #pragma unroll
      for (int j = 0; j < 8; ++j) tmp[j] = fill;
    }
    *(int4*)(Vp + (size_t)idx * 8) = *(int4*)tmp;
  }
}

// ---------------- flash MFMA attention, reg-prefetch staging ----------------
// per iter: issue K/V(kb+1) loads -> compute kb -> barrier -> ds_write -> barrier.
__global__ __launch_bounds__(256, 3) void attn_mfma(const short* __restrict__ Qp,
                                                    const short* __restrict__ Kp,
                                                    const short* __restrict__ Vp,
                                                    __hip_bfloat16* __restrict__ out) {
  __shared__ __align__(16) short Qs[64 * 96];     // 12 KB
  __shared__ __align__(16) short Ks[64 * 96];     // 12 KB
  __shared__ __align__(16) short Vs[64 * 96];     // 12 KB
  __shared__ __align__(16) short Ps[4][16 * 68];  // 8.5 KB, wave-private

  const int qt  = blockIdx.x;
  const int h   = blockIdx.y;
  const int seg = blockIdx.z;
  const int tid  = threadIdx.x;
  const int wave = tid >> 6;
  const int lane = tid & 63;
  const int quad = lane >> 4;
  const int l16  = lane & 15;
  const int sh16 = seg * 16 + h;

  const short* Qg = Qp + (size_t)(sh16 * 16 + qt) * 6144;
  const short* Kg = Kp + (size_t)sh16 * 16 * 6144;
  const short* Vg = Vp + (size_t)sh16 * 16 * 6144;

  // prologue: Q + K/V(0) -> regs -> LDS (one-time vmcnt drain)
  v8s qr[3], kr[3], vr[3];
  #pragma unroll
  for (int it = 0; it < 3; ++it) {
    const int o = (it * 256 + tid) * 8;
    qr[it] = *(const v8s*)(Qg + o);
    kr[it] = *(const v8s*)(Kg + o);
    vr[it] = *(const v8s*)(Vg + o);
  }
  #pragma unroll
  for (int it = 0; it < 3; ++it) {
    const int o = (it * 256 + tid) * 8;
    *(v8s*)&Qs[o] = qr[it];
    *(v8s*)&Ks[o] = kr[it];
    *(v8s*)&Vs[o] = vr[it];
  }
  __syncthreads();

  // Q A-frags: rows wave*16+l16, k-step ks covers d = ks*32 + quad*8 .. +7
  v8s af[3];
  #pragma unroll
  for (int ks = 0; ks < 3; ++ks)
    af[ks] = *(const v8s*)&Qs[((ks * 4 + quad) * 64 + wave * 16 + l16) * 8];

  v4f o4[6];  // n=0..4: O tiles; n=5: ones-column -> row sums l
  const v4f vz = {0.f, 0.f, 0.f, 0.f};
  #pragma unroll
  for (int n = 0; n < 6; ++n) o4[n] = vz;

  for (int kb = 0; kb < 16; ++kb) {
    const bool more = (kb + 1 < 16);
    if (more) {  // issue next-slab loads; wait lands after the compute phase
      const size_t base = (size_t)(kb + 1) * 6144;
      #pragma unroll
      for (int it = 0; it < 3; ++it) {
        const int o = (it * 256 + tid) * 8;
        kr[it] = *(const v8s*)(Kg + base + o);
        vr[it] = *(const v8s*)(Vg + base + o);
      }
    }

    // QK^T: S[16x64] per wave
    v4f s4[4];
    #pragma unroll
    for (int j = 0; j < 4; ++j) {
      s4[j] = vz;
      #pragma unroll
      for (int ks = 0; ks < 3; ++ks) {
        const v8s bf = *(const v8s*)&Ks[((ks * 4 + quad) * 64 + j * 16 + l16) * 8];
        s4[j] = __builtin_amdgcn_mfma_f32_16x16x32_bf16(af[ks], bf, s4[j], 0, 0, 0);
      }
    }

    // p = exp(s) -> wave-private LDS (no max subtraction: |s| small, fp32-safe)
    #pragma unroll
    for (int reg = 0; reg < 4; ++reg)
      #pragma unroll
      for (int j = 0; j < 4; ++j)
        Ps[wave][(quad * 4 + reg) * 68 + j * 16 + l16] = f2bf(__expf(s4[j][reg]));

    // PV (+ ones-column for l)
    v8s pa[2];
    #pragma unroll
    for (int kp = 0; kp < 2; ++kp)
      pa[kp] = *(const v8s*)&Ps[wave][l16 * 68 + kp * 32 + quad * 8];
    #pragma unroll
    for (int n = 0; n < 6; ++n) {
      #pragma unroll
      for (int kp = 0; kp < 2; ++kp) {
        const v8s vb = *(const v8s*)&Vs[((kp * 4 + quad) * 96 + n * 16 + l16) * 8];
        o4[n] = __builtin_amdgcn_mfma_f32_16x16x32_bf16(pa[kp], vb, o4[n], 0, 0, 0);
      }
    }

    __syncthreads();  // all waves done reading Ks/Vs
    if (more) {
      #pragma unroll
      for (int it = 0; it < 3; ++it) {
        const int o = (it * 256 + tid) * 8;
        *(v8s*)&Ks[o] = kr[it];
        *(v8s*)&Vs[o] = vr[it];
      }
    }
    __syncthreads();  // new slab visible
  }

  // l[row] sits in col 80 (n=5, l16==0); broadcast within quad, divide, store
  float inv[4];
  #pragma unroll
  for (int r = 0; r < 4; ++r)
    inv[r] = 1.f / __shfl(o4[5][r], quad << 4);
  const int row0 = seg * SEG + qt * 64 + wave * 16 + quad * 4;
  #pragma unroll
  for (int n = 0; n < 5; ++n) {
    const int col = h * HD + n * 16 + l16;
    #pragma unroll
    for (int r = 0; r < 4; ++r)
      out[(size_t)(row0 + r) * DIM + col] = __float2bfloat16(o4[n][r] * inv[r]);
  }
}

extern "C" void kernel_launch(void* const* d_in, const int* in_sizes, int n_in,
                              void* d_out, int out_size, void* d_ws, size_t ws_size,
                              hipStream_t stream) {
  (void)in_sizes; (void)n_in; (void)out_size; (void)ws_size;
  const float* hs     = (const float*)d_in[0];
  const float* cosp   = (const float*)d_in[1];
  const float* sinp   = (const float*)d_in[2];
  const float* qkv_w  = (const float*)d_in[3];
  const float* qkv_b  = (const float*)d_in[4];
  const float* proj_w = (const float*)d_in[5];
  const float* proj_b = (const float*)d_in[6];

  float* out_f = (float*)d_out;
  __hip_bfloat16* qkv_b16 = (__hip_bfloat16*)d_ws;                     // [A]
  __hip_bfloat16* hs_b    = qkv_b16 + (size_t)S_TOT * TDIM;            // [B]
  __hip_bfloat16* qkvw_b  = hs_b + (size_t)S_TOT * DIM;                // [C]
  __hip_bfloat16* projw_b = qkvw_b + (size_t)TDIM * DIM;               // [D]
  short* Qp = (short*)qkvw_b;                                          // alias [C]
  short* Kp = (short*)(projw_b + (size_t)DIM * DIM);                   // [E]
  short* Vp = Kp + (size_t)3 * 16 * 16 * 6144;                         // [F]
  __hip_bfloat16* attn_b = hs_b;                                       // alias [B]

  cvt3<<<(CVT_N1 + CVT_N2 + CVT_N3) / 256, 256, 0, stream>>>(
      hs, qkv_w, proj_w, hs_b, qkvw_b, projw_b);

  gemm128_db2<<<dim3(TDIM / 128, S_TOT / 128), 256, 0, stream>>>(
      hs_b, qkvw_b, qkv_b, qkv_b16, S_TOT, TDIM, DIM);

  pack_all<<<QK_BLOCKS + V_BLOCKS, 256, 0, stream>>>(qkv_b16, cosp, sinp, Qp, Kp, Vp);

  attn_mfma<<<dim3(16, NH, 3), 256, 0, stream>>>(Qp, Kp, Vp, attn_b);

  gemm2_db<<<dim3(DIM / 128, S_TOT / 64), 256, 0, stream>>>(
      attn_b, projw_b, proj_b, out_f, S_TOT, DIM, DIM);
}